// Round 6
// baseline (630.197 us; speedup 1.0000x reference)
//
#include <hip/hip_runtime.h>

typedef float    f32x4  __attribute__((ext_vector_type(4)));
typedef float    f32x16 __attribute__((ext_vector_type(16)));
typedef _Float16 f16x4  __attribute__((ext_vector_type(4)));
typedef _Float16 f16x8  __attribute__((ext_vector_type(8)));

#define N_IMG 50000
#define BROWS 256
#define CHW   3072
#define BK    64
#define BM    128
#define BN    128
#define EHS   50176       // padded k stride (zeros beyond 50000) for eh and imgT
#define KCHUNK 3136       // 49*64 split-K chunk for GEMM2
#define NSPLIT 16
#define TPITCH 136        // prep transpose-tile pitch (272B rows, 16B aligned)

// direct global->LDS (wave-uniform LDS base + lane*16B; per-lane global addr)
__device__ __forceinline__ void glds16(const void* g, void* l) {
    __builtin_amdgcn_global_load_lds(
        (const __attribute__((address_space(1))) void*)g,
        (__attribute__((address_space(3))) void*)l, 16, 0, 0);
}

// ---------------- scalars from t ----------------
__global__ void k_scalars(const float* __restrict__ t, float* __restrict__ sc) {
    if (threadIdx.x == 0) {
        double tv  = (double)t[0];
        double ang = tv * (1.5707963267948966 / 1.008);
        double c   = cos(ang);
        double at  = c;
        double bt2 = 1.0 - c * c;
        sc[0] = (float)at;
        sc[1] = (float)bt2;
        sc[2] = (float)(at / bt2);             // c_cross
        sc[3] = (float)(at * at * 0.5 / bt2);  // c_y2
        sc[4] = (float)(1.0 / bt2);            // inv_bt2
    }
}

// ---------------- x -> f16 ----------------
// -||x||^2 logit term is a per-row constant -> cancelled by row softmax; omitted.
__global__ void k_xprep(const float* __restrict__ x, _Float16* __restrict__ xh) {
    int idx = blockIdx.x * 256 + threadIdx.x;
    f32x4 v = ((const f32x4*)x)[idx];
    f16x4 h;
    h[0] = (_Float16)v[0]; h[1] = (_Float16)v[1];
    h[2] = (_Float16)v[2]; h[3] = (_Float16)v[3];
    ((f16x4*)xh)[idx] = h;
}

// ---------------- img f32 -> imgh f16 [n][d], imgT f16 [d][n], y2 ----------------
// One streaming pass; 128x128 tiles; LDS transpose. HBM-bound (~1.23 GB total).
__global__ __launch_bounds__(256) void k_prep(const float* __restrict__ img,
        _Float16* __restrict__ imgh, _Float16* __restrict__ imgT,
        float* __restrict__ y2) {
    __shared__ _Float16 LT[128 * TPITCH];   // 34 KB
    const int tid = threadIdx.x;
    const int n0 = blockIdx.x * 128;
    const int d0 = blockIdx.y * 128;
    const int rbase = tid >> 5;          // 0..7
    const int dcol  = (tid & 31) * 4;    // 0..124

    for (int i = 0; i < 16; i++) {
        int nl = rbase + i * 8;          // 0..127
        int n  = n0 + nl;
        bool valid = n < N_IMG;
        int nc = valid ? n : (N_IMG - 1);
        f32x4 v = *(const f32x4*)(img + (size_t)nc * CHW + d0 + dcol);
        if (!valid) { v[0] = 0.f; v[1] = 0.f; v[2] = 0.f; v[3] = 0.f; }
        float s = v[0]*v[0] + v[1]*v[1] + v[2]*v[2] + v[3]*v[3];
        s += __shfl_xor(s, 1); s += __shfl_xor(s, 2); s += __shfl_xor(s, 4);
        s += __shfl_xor(s, 8); s += __shfl_xor(s, 16);
        if ((tid & 31) == 0 && valid) atomicAdd(&y2[n], s);
        f16x4 h;
        h[0] = (_Float16)v[0]; h[1] = (_Float16)v[1];
        h[2] = (_Float16)v[2]; h[3] = (_Float16)v[3];
        if (valid) *(f16x4*)(imgh + (size_t)n * CHW + d0 + dcol) = h;
        #pragma unroll
        for (int j = 0; j < 4; j++) LT[(dcol + j) * TPITCH + nl] = h[j];
    }
    __syncthreads();

    const int dl = tid >> 1;             // 0..127
    const int nh = (tid & 1) * 64;
    const f16x8* src = (const f16x8*)&LT[dl * TPITCH + nh];
    f16x8* dst = (f16x8*)(imgT + (size_t)(d0 + dl) * EHS + n0 + nh);
    #pragma unroll
    for (int g = 0; g < 8; g++) dst[g] = src[g];
}

// ---------------- GEMM1: logits = c_cross*(xh@imghT) - c_y2*y2 ----------------
// m97 structure: 128x128x64, glds width16 both tiles, XOR-swizzled LDS,
// 4 waves (2x2 of 64x64), 32x32x16_f16.  (proven in R4)
__global__ __launch_bounds__(256, 3) void k_gemm1(
        const _Float16* __restrict__ xh, const _Float16* __restrict__ imgh,
        const float* __restrict__ y2g, const float* __restrict__ sc,
        float* __restrict__ logits) {
    __shared__ _Float16 Alds[BM * BK];   // 16 KB, [row][g^(row&7)] 16B granules
    __shared__ _Float16 Blds[BN * BK];   // 16 KB

    const int tid = threadIdx.x;
    const int wid = tid >> 6, lane = tid & 63;
    const int m0 = blockIdx.x * BM;
    const int n0 = blockIdx.y * BN;

    const _Float16* gA[4]; const _Float16* gB[4];
    _Float16* lA[4]; _Float16* lB[4];
    #pragma unroll
    for (int j = 0; j < 4; j++) {
        int seg = wid * 4 + j;
        int row = seg * 8 + (lane >> 3);
        int off = (((lane & 7) ^ (row & 7)) << 3);   // f16 elements
        gA[j] = xh + (size_t)(m0 + row) * CHW + off;
        int rb = n0 + row; if (rb > N_IMG - 1) rb = N_IMG - 1;
        gB[j] = imgh + (size_t)rb * CHW + off;
        lA[j] = Alds + seg * 512;
        lB[j] = Blds + seg * 512;
    }

    const int wm = wid >> 1, wn = wid & 1;
    const int rm = wm * 64, cn = wn * 64;
    const int lr = lane & 31, hi = lane >> 5;
    const int xm = (lr & 7) << 4;                    // read-side byte XOR
    const char* Ab = (const char*)Alds;
    const char* Bb = (const char*)Blds;
    const int ar0 = (rm + lr) * 128,      ar1 = (rm + 32 + lr) * 128;
    const int br0 = (cn + lr) * 128,      br1 = (cn + 32 + lr) * 128;
    const int kof = hi * 16;

    f32x16 acc[2][2];
    #pragma unroll
    for (int mi = 0; mi < 2; mi++)
        #pragma unroll
        for (int ni = 0; ni < 2; ni++)
            #pragma unroll
            for (int r = 0; r < 16; r++) acc[mi][ni][r] = 0.f;

    for (int it = 0; it < CHW / BK; ++it) {
        if (it) __syncthreads();
        #pragma unroll
        for (int j = 0; j < 4; j++) glds16(gA[j] + it * BK, lA[j]);
        #pragma unroll
        for (int j = 0; j < 4; j++) glds16(gB[j] + it * BK, lB[j]);
        __syncthreads();
        #pragma unroll
        for (int ks = 0; ks < 4; ++ks) {
            int off = (ks * 32 + kof) ^ xm;
            f16x8 a0 = *(const f16x8*)(Ab + ar0 + off);
            f16x8 a1 = *(const f16x8*)(Ab + ar1 + off);
            f16x8 b0 = *(const f16x8*)(Bb + br0 + off);
            f16x8 b1 = *(const f16x8*)(Bb + br1 + off);
            acc[0][0] = __builtin_amdgcn_mfma_f32_32x32x16_f16(a0, b0, acc[0][0], 0, 0, 0);
            acc[0][1] = __builtin_amdgcn_mfma_f32_32x32x16_f16(a0, b1, acc[0][1], 0, 0, 0);
            acc[1][0] = __builtin_amdgcn_mfma_f32_32x32x16_f16(a1, b0, acc[1][0], 0, 0, 0);
            acc[1][1] = __builtin_amdgcn_mfma_f32_32x32x16_f16(a1, b1, acc[1][1], 0, 0, 0);
        }
    }

    const float c_cross = sc[2], c_y2 = sc[3];
    #pragma unroll
    for (int mi = 0; mi < 2; mi++)
        #pragma unroll
        for (int ni = 0; ni < 2; ni++) {
            int col = n0 + cn + ni * 32 + lr;
            if (col >= N_IMG) continue;
            float y2v = y2g[col];
            f32x16 v = acc[mi][ni];
            #pragma unroll
            for (int r = 0; r < 16; r++) {
                int row = m0 + rm + mi * 32 + (r & 3) + 8 * (r >> 2) + 4 * hi;
                logits[(size_t)row * N_IMG + col] = c_cross * v[r] - c_y2 * y2v;
            }
        }
}

// ---------------- fused row max + exp + row sum (writes padded eh) ----------------
__global__ void k_softmax(const float* __restrict__ logits, _Float16* __restrict__ eh,
                          float* __restrict__ rowsum) {
    int row = blockIdx.x, tid = threadIdx.x;
    const f32x4* lr = (const f32x4*)(logits + (size_t)row * N_IMG);
    _Float16* erow = eh + (size_t)row * EHS;
    f16x4* er = (f16x4*)erow;
    __shared__ float wred[4];

    if (tid < EHS - N_IMG) erow[N_IMG + tid] = (_Float16)0.f;   // zero K-tail pad

    float m = -3.0e38f;
    for (int i = tid; i < N_IMG / 4; i += 256) {
        f32x4 v = lr[i];
        m = fmaxf(m, fmaxf(fmaxf(v[0], v[1]), fmaxf(v[2], v[3])));
    }
    for (int o = 32; o > 0; o >>= 1) m = fmaxf(m, __shfl_down(m, o));
    if ((tid & 63) == 0) wred[tid >> 6] = m;
    __syncthreads();
    m = fmaxf(fmaxf(wred[0], wred[1]), fmaxf(wred[2], wred[3]));
    __syncthreads();

    float s = 0.f;
    for (int i = tid; i < N_IMG / 4; i += 256) {
        f32x4 v = lr[i];
        float e0 = __expf(v[0] - m), e1 = __expf(v[1] - m);
        float e2 = __expf(v[2] - m), e3 = __expf(v[3] - m);
        s += (e0 + e1) + (e2 + e3);
        f16x4 h;
        h[0] = (_Float16)e0; h[1] = (_Float16)e1;
        h[2] = (_Float16)e2; h[3] = (_Float16)e3;
        er[i] = h;
    }
    for (int o = 32; o > 0; o >>= 1) s += __shfl_down(s, o);
    if ((tid & 63) == 0) wred[tid >> 6] = s;
    __syncthreads();
    if (tid == 0) rowsum[row] = (wred[0] + wred[1]) + (wred[2] + wred[3]);
}

// ---------------- GEMM2: partial[ck] = eh[:,chunk] @ imgT^T[chunk,:] ----------------
// All-glds, same m97 structure as gemm1. A = eh [b][n], B = imgT [d][n];
// both padded to EHS with zeros -> uniform 49 iters, no tail logic.
__global__ __launch_bounds__(256, 3) void k_gemm2(
        const _Float16* __restrict__ eh, const _Float16* __restrict__ imgT,
        float* __restrict__ partial) {
    __shared__ _Float16 Alds[BM * BK];   // 16 KB
    __shared__ _Float16 Blds[BN * BK];   // 16 KB

    const int tid = threadIdx.x;
    const int wid = tid >> 6, lane = tid & 63;
    const int m0 = blockIdx.x * BM;
    const int d0 = blockIdx.y * BN;
    const int kbase = blockIdx.z * KCHUNK;

    const _Float16* gA[4]; const _Float16* gB[4];
    _Float16* lA[4]; _Float16* lB[4];
    #pragma unroll
    for (int j = 0; j < 4; j++) {
        int seg = wid * 4 + j;
        int row = seg * 8 + (lane >> 3);
        int off = (((lane & 7) ^ (row & 7)) << 3);
        gA[j] = eh   + (size_t)(m0 + row) * EHS + kbase + off;
        gB[j] = imgT + (size_t)(d0 + row) * EHS + kbase + off;
        lA[j] = Alds + seg * 512;
        lB[j] = Blds + seg * 512;
    }

    const int wm = wid >> 1, wn = wid & 1;
    const int rm = wm * 64, cn = wn * 64;
    const int lr = lane & 31, hi = lane >> 5;
    const int xm = (lr & 7) << 4;
    const char* Ab = (const char*)Alds;
    const char* Bb = (const char*)Blds;
    const int ar0 = (rm + lr) * 128,      ar1 = (rm + 32 + lr) * 128;
    const int br0 = (cn + lr) * 128,      br1 = (cn + 32 + lr) * 128;
    const int kof = hi * 16;

    f32x16 acc[2][2];
    #pragma unroll
    for (int mi = 0; mi < 2; mi++)
        #pragma unroll
        for (int ni = 0; ni < 2; ni++)
            #pragma unroll
            for (int r = 0; r < 16; r++) acc[mi][ni][r] = 0.f;

    for (int it = 0; it < KCHUNK / BK; ++it) {
        if (it) __syncthreads();
        #pragma unroll
        for (int j = 0; j < 4; j++) glds16(gA[j] + it * BK, lA[j]);
        #pragma unroll
        for (int j = 0; j < 4; j++) glds16(gB[j] + it * BK, lB[j]);
        __syncthreads();
        #pragma unroll
        for (int ks = 0; ks < 4; ++ks) {
            int off = (ks * 32 + kof) ^ xm;
            f16x8 a0 = *(const f16x8*)(Ab + ar0 + off);
            f16x8 a1 = *(const f16x8*)(Ab + ar1 + off);
            f16x8 b0 = *(const f16x8*)(Bb + br0 + off);
            f16x8 b1 = *(const f16x8*)(Bb + br1 + off);
            acc[0][0] = __builtin_amdgcn_mfma_f32_32x32x16_f16(a0, b0, acc[0][0], 0, 0, 0);
            acc[0][1] = __builtin_amdgcn_mfma_f32_32x32x16_f16(a0, b1, acc[0][1], 0, 0, 0);
            acc[1][0] = __builtin_amdgcn_mfma_f32_32x32x16_f16(a1, b0, acc[1][0], 0, 0, 0);
            acc[1][1] = __builtin_amdgcn_mfma_f32_32x32x16_f16(a1, b1, acc[1][1], 0, 0, 0);
        }
    }

    float* pp = partial + (size_t)blockIdx.z * BROWS * CHW;
    #pragma unroll
    for (int mi = 0; mi < 2; mi++)
        #pragma unroll
        for (int ni = 0; ni < 2; ni++) {
            int dcol = d0 + cn + ni * 32 + lr;
            f32x16 v = acc[mi][ni];
            #pragma unroll
            for (int r = 0; r < 16; r++) {
                int row = m0 + rm + mi * 32 + (r & 3) + 8 * (r >> 2) + 4 * hi;
                pp[(size_t)row * CHW + dcol] = v[r];
            }
        }
}

// ---------------- reduce partials + final score ----------------
__global__ void k_final(const float* __restrict__ partial, const float* __restrict__ x,
                        const float* __restrict__ rowsum, const float* __restrict__ sc,
                        float* __restrict__ out) {
    int idx = blockIdx.x * 256 + threadIdx.x;
    int row = idx / (CHW / 4);
    float at = sc[0], invbt2 = sc[4];
    float scale = at * invbt2 / rowsum[row];
    const f32x4* p4 = (const f32x4*)partial;
    f32x4 s = p4[idx];
    #pragma unroll
    for (int c = 1; c < NSPLIT; c++) s = s + p4[(size_t)c * (BROWS * CHW / 4) + idx];
    f32x4 xv = ((const f32x4*)x)[idx];
    f32x4 o;
    #pragma unroll
    for (int j = 0; j < 4; j++) o[j] = s[j] * scale - xv[j] * invbt2;
    ((f32x4*)out)[idx] = o;
}

extern "C" void kernel_launch(void* const* d_in, const int* in_sizes, int n_in,
                              void* d_out, int out_size, void* d_ws, size_t ws_size,
                              hipStream_t stream) {
    const float* t   = (const float*)d_in[0];
    const float* x   = (const float*)d_in[1];
    const float* img = (const float*)d_in[2];
    float* out = (float*)d_out;
    char* ws = (char*)d_ws;

    // ws layout (bytes)
    float*    sc     = (float*)(ws + 0);                   // 64 B
    float*    rowsum = (float*)(ws + 256);                 // 1 KB
    float*    y2     = (float*)(ws + 4096);                // 200 KB
    _Float16* xh     = (_Float16*)(ws + 212992);           // 1.5 MB
    _Float16* imgh   = (_Float16*)(ws + 2097152);          // 307.2 MB [n][d]
    _Float16* imgT   = (_Float16*)(ws + 309297152);        // 308.3 MB [d][EHS]
    _Float16* eh     = (_Float16*)(ws + 617578496);        // 25.7 MB  [b][EHS]
    float*    logits = (float*)(ws + 643268608);           // 51.2 MB
    float*    partial = logits;                            // reused (50.4 MB)

    k_scalars<<<1, 64, 0, stream>>>(t, sc);
    k_xprep<<<(BROWS * CHW / 4) / 256, 256, 0, stream>>>(x, xh);
    hipMemsetAsync(y2, 0, N_IMG * sizeof(float), stream);
    k_prep<<<dim3((N_IMG + 127) / 128, CHW / 128), 256, 0, stream>>>(img, imgh, imgT, y2);
    k_gemm1<<<dim3(2, (N_IMG + BN - 1) / BN), 256, 0, stream>>>(xh, imgh, y2, sc, logits);
    k_softmax<<<256, 256, 0, stream>>>(logits, eh, rowsum);
    k_gemm2<<<dim3(2, CHW / BN, NSPLIT), 256, 0, stream>>>(eh, imgT, partial);
    k_final<<<(BROWS * CHW / 4) / 256, 256, 0, stream>>>(partial, x, rowsum, sc, out);
}